// Round 2
// baseline (604.859 us; speedup 1.0000x reference)
//
#include <hip/hip_runtime.h>

// FFF binary-tree routing, MI355X — fp32 in/out (round-1 NaN proved inputs are fp32).
// x[65536,1024] f32, X[1023,1024] f32, Y[1023,1024] f32 -> y[65536,1024] f32.
// One wave per sample. Lane l owns elements {c*256 + 4l + j : c in 0..3, j in 0..3}
// so every float4 instruction is a perfectly coalesced 1KB wave access.
// Dot product in fp64 (per-lane FMA + fp64 butterfly) so the sign(lam) routing
// decision matches the true sign — fp32 ordering noise (~2e-6) across 655k
// decisions would otherwise flip ~1 route per run and blow absmax.

constexpr int DEPTH = 10;
constexpr int N_IN  = 1024;
constexpr int N_OUT = 1024;

__global__ __launch_bounds__(256) void fff_fwd(
        const float* __restrict__ xg,
        const float* __restrict__ Xg,
        const float* __restrict__ Yg,
        float* __restrict__ outg,
        int n_batch)
{
    const int lane = threadIdx.x & 63;
    const int wave = blockIdx.x * (blockDim.x >> 6) + (threadIdx.x >> 6);
    if (wave >= n_batch) return;

    // ---- load this sample's x: 4 coalesced float4 chunks ----
    const float4* xp = reinterpret_cast<const float4*>(xg + (size_t)wave * N_IN) + lane;
    float4 xv[4];
#pragma unroll
    for (int c = 0; c < 4; ++c) xv[c] = xp[c * 64];

    float4 acc[4];
#pragma unroll
    for (int c = 0; c < 4; ++c) acc[c] = make_float4(0.f, 0.f, 0.f, 0.f);

    int node = 0;
#pragma unroll
    for (int d = 0; d < DEPTH; ++d) {
        const float4* Xp = reinterpret_cast<const float4*>(Xg + (size_t)node * N_IN) + lane;
        const float4* Yp = reinterpret_cast<const float4*>(Yg + (size_t)node * N_IN) + lane;
        float4 xr[4], yr[4];
#pragma unroll
        for (int c = 0; c < 4; ++c) xr[c] = Xp[c * 64];
#pragma unroll
        for (int c = 0; c < 4; ++c) yr[c] = Yp[c * 64];

        // ---- dot(x, X[node]) in fp64 for routing-sign fidelity ----
        double p = 0.0;
#pragma unroll
        for (int c = 0; c < 4; ++c) {
            p = fma((double)xv[c].x, (double)xr[c].x, p);
            p = fma((double)xv[c].y, (double)xr[c].y, p);
            p = fma((double)xv[c].z, (double)xr[c].z, p);
            p = fma((double)xv[c].w, (double)xr[c].w, p);
        }
        // 64-lane butterfly (bit-identical on every lane)
#pragma unroll
        for (int off = 32; off > 0; off >>= 1)
            p += __shfl_xor(p, off, 64);

        const float lam = (float)p;

        // ---- y += lam * Y[node] (fp32) ----
#pragma unroll
        for (int c = 0; c < 4; ++c) {
            acc[c].x = fmaf(lam, yr[c].x, acc[c].x);
            acc[c].y = fmaf(lam, yr[c].y, acc[c].y);
            acc[c].z = fmaf(lam, yr[c].z, acc[c].z);
            acc[c].w = fmaf(lam, yr[c].w, acc[c].w);
        }

        // ---- branch: node = 2*node + 1 + (lam > 0); wave-uniform -> scalarize ----
        const int go_right = (p > 0.0) ? 1 : 0;
        node = __builtin_amdgcn_readfirstlane(node * 2 + 1 + go_right);
    }

    // ---- coalesced float4 store ----
    float4* op = reinterpret_cast<float4*>(outg + (size_t)wave * N_OUT) + lane;
#pragma unroll
    for (int c = 0; c < 4; ++c) op[c * 64] = acc[c];
}

extern "C" void kernel_launch(void* const* d_in, const int* in_sizes, int n_in,
                              void* d_out, int out_size, void* d_ws, size_t ws_size,
                              hipStream_t stream) {
    const float* x = (const float*)d_in[0];
    const float* X = (const float*)d_in[1];
    const float* Y = (const float*)d_in[2];
    float* out = (float*)d_out;

    const int n_batch = in_sizes[0] / N_IN;          // 65536
    const int waves_per_block = 4;                   // 256 threads
    const int blocks = (n_batch + waves_per_block - 1) / waves_per_block;

    fff_fwd<<<blocks, 256, 0, stream>>>(x, X, Y, out, n_batch);
}